// Round 2
// baseline (155.498 us; speedup 1.0000x reference)
//
#include <hip/hip_runtime.h>

#define HW_    12544   // 112*112
#define W_     112
#define C_     128
#define OHW_   3136    // 56*56
#define OW_    56
#define NCHUNK 98

// Pass 1: per-(batch, chunk) partial sums of squares per phase -> ws.
// grid = (98, 32), 256 threads, 16 float4 per thread.
__global__ __launch_bounds__(256) void phase_norms(const float* __restrict__ inp,
                                                   float* __restrict__ part) {
    const int b = blockIdx.y;
    const float4* src = (const float4*)(inp + (size_t)b * (C_ * HW_));
    const unsigned tid = threadIdx.x;
    const unsigned base = blockIdx.x * 4096u + tid;

    float s[4] = {0.f, 0.f, 0.f, 0.f};
#pragma unroll
    for (int k = 0; k < 16; ++k) {
        unsigned g = base + k * 256u;
        float4 v = src[g];
        unsigned hp = (g / 28u) & 1u;      // 28 float4 per row
        s[hp]      += v.x * v.x + v.z * v.z;   // even w -> phases 0/1 (h parity)
        s[hp + 2u] += v.y * v.y + v.w * v.w;   // odd  w -> phases 2/3
    }

#pragma unroll
    for (int p = 0; p < 4; ++p) {
        float v = s[p];
        for (int off = 32; off > 0; off >>= 1) v += __shfl_down(v, off);
        s[p] = v;
    }

    __shared__ float bs[4][4];             // [wave][phase]
    const unsigned wid = tid >> 6;
    if ((tid & 63u) == 0u) {
#pragma unroll
        for (int p = 0; p < 4; ++p) bs[wid][p] = s[p];
    }
    __syncthreads();
    if (tid < 4) {
        float v = bs[0][tid] + bs[1][tid] + bs[2][tid] + bs[3][tid];
        part[((size_t)b * NCHUNK + blockIdx.x) * 4 + tid] = v;
    }
}

// Pass 2: one block (448 thr = 7 waves) per (b,c) plane. No LDS staging —
// input is L2/L3-resident after pass 1. Each thread: 1x7 output strip,
// separable [1,3,3,1] blur, branchless reflect indexing.
__global__ __launch_bounds__(448) void blur_select(const float* __restrict__ inp,
                                                   const float* __restrict__ part,
                                                   float* __restrict__ out) {
    const int bc = blockIdx.x;
    const int b  = bc >> 7;                // / C_
    const int t  = threadIdx.x;

    // deterministic reduction of 98 chunk-partials; wave w handles phase w
    __shared__ float s4[4];
    {
        const int wid = t >> 6, lane = t & 63;
        if (wid < 4) {
            const float* pp = part + (size_t)b * NCHUNK * 4 + wid;
            float v = (lane < NCHUNK) ? pp[lane * 4] : 0.f;
            if (lane + 64 < NCHUNK) v += pp[(lane + 64) * 4];
            for (int off = 32; off > 0; off >>= 1) v += __shfl_down(v, off);
            if (lane == 0) s4[wid] = v;
        }
    }
    __syncthreads();
    const float n0 = s4[0], n1 = s4[1], n2 = s4[2], n3 = s4[3];
    int idx = 0; float best = n0;
    if (n1 > best) { best = n1; idx = 1; }
    if (n2 > best) { best = n2; idx = 2; }
    if (n3 > best) { best = n3; idx = 3; }
    const int dr = idx & 1, dc = idx >> 1;

    const int oh  = t >> 3;                // 0..55
    const int st  = t & 7;                 // 0..7
    const int ow0 = st * 7;                // strips of 7 -> 56 cols
    const float* P = inp + (size_t)bc * HW_;

    // 4 input rows with reflect: reflect(j) = min(abs(j), 222-abs(j))
    const float* rows[4];
    const int rb = oh * 2 + dr - 1;
#pragma unroll
    for (int k = 0; k < 4; ++k) {
        int j = rb + k;
        int aj = j < 0 ? -j : j;
        j = min(aj, 222 - aj);
        rows[k] = P + j * W_;
    }

    // 16 col indices with reflect (shared across the 4 rows)
    int cidx[16];
    const int cb = ow0 * 2 + dc - 1;
#pragma unroll
    for (int m = 0; m < 16; ++m) {
        int j = cb + m;
        int aj = j < 0 ? -j : j;
        cidx[m] = min(aj, 222 - aj);
    }

    float h[4][7];
#pragma unroll
    for (int k = 0; k < 4; ++k) {
        float x[16];
#pragma unroll
        for (int m = 0; m < 16; ++m) x[m] = rows[k][cidx[m]];
#pragma unroll
        for (int j = 0; j < 7; ++j)
            h[k][j] = (x[2*j] + x[2*j+3]) + 3.f * (x[2*j+1] + x[2*j+2]);
    }

    float* o = out + (size_t)bc * OHW_ + oh * OW_ + ow0;
#pragma unroll
    for (int j = 0; j < 7; ++j)
        o[j] = ((h[0][j] + h[3][j]) + 3.f * (h[1][j] + h[2][j])) * 0.015625f;
}

extern "C" void kernel_launch(void* const* d_in, const int* in_sizes, int n_in,
                              void* d_out, int out_size, void* d_ws, size_t ws_size,
                              hipStream_t stream) {
    const float* inp = (const float*)d_in[0];
    float* part = (float*)d_ws;            // 32*98*4 floats = 50 KB
    phase_norms<<<dim3(NCHUNK, 32), 256, 0, stream>>>(inp, part);
    blur_select<<<4096, 448, 0, stream>>>(inp, part, (float*)d_out);
}

// Round 3
// 89.931 us; speedup vs baseline: 1.7291x; 1.7291x over previous
//
#include <hip/hip_runtime.h>

#define HW_    12544   // 112*112
#define W_     112
#define C_     128
#define OHW_   3136    // 56*56
#define OW_    56
#define NCHUNK 98

#define TROWS  28      // output rows per block (2 blocks per plane)
#define IROWS  59      // staged input rows = 28*2 + 3
#define LDSW   116     // padded LDS row stride (cols q=0..114 used)

// Pass 1: per-(batch, chunk) partial sums of squares per phase -> ws.
// grid = (98, 32), 256 threads, 16 float4 per thread. (~roofline, unchanged)
__global__ __launch_bounds__(256) void phase_norms(const float* __restrict__ inp,
                                                   float* __restrict__ part) {
    const int b = blockIdx.y;
    const float4* src = (const float4*)(inp + (size_t)b * (C_ * HW_));
    const unsigned tid = threadIdx.x;
    const unsigned base = blockIdx.x * 4096u + tid;

    float s[4] = {0.f, 0.f, 0.f, 0.f};
#pragma unroll
    for (int k = 0; k < 16; ++k) {
        unsigned g = base + k * 256u;
        float4 v = src[g];
        unsigned hp = (g / 28u) & 1u;          // 28 float4 per row
        s[hp]      += v.x * v.x + v.z * v.z;   // even w -> phases 0/1
        s[hp + 2u] += v.y * v.y + v.w * v.w;   // odd  w -> phases 2/3
    }

#pragma unroll
    for (int p = 0; p < 4; ++p) {
        float v = s[p];
        for (int off = 32; off > 0; off >>= 1) v += __shfl_down(v, off);
        s[p] = v;
    }

    __shared__ float bs[4][4];
    const unsigned wid = tid >> 6;
    if ((tid & 63u) == 0u) {
#pragma unroll
        for (int p = 0; p < 4; ++p) bs[wid][p] = s[p];
    }
    __syncthreads();
    if (tid < 4) {
        float v = bs[0][tid] + bs[1][tid] + bs[2][tid] + bs[3][tid];
        part[((size_t)b * NCHUNK + blockIdx.x) * 4 + tid] = v;
    }
}

// Pass 2: strip-mined. Block = 28 output rows of one plane.
// 512 threads (8 waves), 27.4 KB LDS -> 4 blocks/CU = 32 waves/CU.
// Reflect handled entirely at stage time (padded tile); inner loop branchless.
__global__ __launch_bounds__(512) void blur_select(const float* __restrict__ inp,
                                                   const float* __restrict__ part,
                                                   float* __restrict__ out) {
    __shared__ float tile[IROWS * LDSW];
    __shared__ float s4[4];

    const int blk = blockIdx.x;
    const int bc  = blk >> 1;                  // plane index
    const int b   = bc >> 7;                   // batch
    const int oh0 = (blk & 1) * TROWS;         // 0 or 28
    const int t   = threadIdx.x;

    // ---- argmax inputs: deterministic reduce of 98 partials (waves 0-3) ----
    {
        const int wid = t >> 6, lane = t & 63;
        if (wid < 4) {
            const float* pp = part + (size_t)b * NCHUNK * 4 + wid;
            float v = (lane < NCHUNK) ? pp[lane * 4] : 0.f;
            if (lane + 64 < NCHUNK) v += pp[(lane + 64) * 4];
            for (int off = 32; off > 0; off >>= 1) v += __shfl_down(v, off);
            if (lane == 0) s4[wid] = v;
        }
    }

    // ---- stage 59 reflect-mapped rows, reflect-padded cols ----
    const float* P = inp + (size_t)bc * HW_;
    const int jbase = oh0 * 2 - 1;
    // main body: coalesced float4 (59 rows x 28 float4)
    for (int i = t; i < IROWS * 28; i += 512) {
        const int row = i / 28, c4 = i - row * 28;
        int j = jbase + row;
        int aj = j < 0 ? -j : j;
        j = min(aj, 222 - aj);
        const float4 v = ((const float4*)(P + j * W_))[c4];
        float* dst = &tile[row * LDSW + 1 + 4 * c4];
        dst[0] = v.x; dst[1] = v.y; dst[2] = v.z; dst[3] = v.w;
    }
    // edge pads: q=0 -> col -1 -> 1 ; q=113 -> col 112 -> 110 ; q=114 -> col 113 -> 109
    if (t < IROWS) {
        int j = jbase + t;
        int aj = j < 0 ? -j : j;
        j = min(aj, 222 - aj);
        const float* R = P + j * W_;
        tile[t * LDSW + 0]   = R[1];
        tile[t * LDSW + 113] = R[110];
        tile[t * LDSW + 114] = R[109];
    }
    __syncthreads();

    const float n0 = s4[0], n1 = s4[1], n2 = s4[2], n3 = s4[3];
    int idx = 0; float best = n0;
    if (n1 > best) { best = n1; idx = 1; }
    if (n2 > best) { best = n2; idx = 2; }
    if (n3 > best) { best = n3; idx = 3; }
    const int dr = idx & 1, dc = idx >> 1;

    // ---- compute: 28*56 = 1568 outputs, 16 LDS reads + separable FMA each ----
    float* o = out + (size_t)bc * OHW_ + oh0 * OW_;
    for (int e = t; e < TROWS * OW_; e += 512) {
        const int ohl = e / OW_;
        const int ow  = e - ohl * OW_;
        const float* base = &tile[(ohl * 2 + dr) * LDSW + ow * 2 + dc];
        float acc = 0.f;
#pragma unroll
        for (int k = 0; k < 4; ++k) {
            const float* r = base + k * LDSW;
            const float h = (r[0] + r[3]) + 3.f * (r[1] + r[2]);
            acc += (k == 1 || k == 2) ? 3.f * h : h;
        }
        o[e] = acc * 0.015625f;
    }
}

extern "C" void kernel_launch(void* const* d_in, const int* in_sizes, int n_in,
                              void* d_out, int out_size, void* d_ws, size_t ws_size,
                              hipStream_t stream) {
    const float* inp = (const float*)d_in[0];
    float* part = (float*)d_ws;                // 32*98*4 floats = 50 KB
    phase_norms<<<dim3(NCHUNK, 32), 256, 0, stream>>>(inp, part);
    blur_select<<<8192, 512, 0, stream>>>(inp, part, (float*)d_out);
}

// Round 4
// 88.718 us; speedup vs baseline: 1.7527x; 1.0137x over previous
//
#include <hip/hip_runtime.h>

#define HW_    12544   // 112*112
#define W_     112
#define C_     128
#define OHW_   3136    // 56*56
#define OW_    56
#define NCHUNK 49      // chunks per batch sample (8192 float4 each)

// ---------------- Pass 1: per-(batch,chunk) phase sums of squares ----------------
// grid = (49, 32), 512 threads, 16 float4/thread.
__global__ __launch_bounds__(512) void phase_norms(const float* __restrict__ inp,
                                                   float* __restrict__ part) {
    const int b = blockIdx.y;
    const float4* src = (const float4*)(inp + (size_t)b * (C_ * HW_));
    const unsigned tid = threadIdx.x;
    const unsigned base = blockIdx.x * 8192u + tid;

    float s[4] = {0.f, 0.f, 0.f, 0.f};
#pragma unroll
    for (int k = 0; k < 16; ++k) {
        unsigned g = base + k * 512u;
        float4 v = src[g];
        unsigned hp = (g / 28u) & 1u;          // 28 float4 per row
        s[hp]      += v.x * v.x + v.z * v.z;   // even w -> phases 0/1
        s[hp + 2u] += v.y * v.y + v.w * v.w;   // odd  w -> phases 2/3
    }

#pragma unroll
    for (int p = 0; p < 4; ++p) {
        float v = s[p];
        for (int off = 32; off > 0; off >>= 1) v += __shfl_down(v, off);
        s[p] = v;
    }

    __shared__ float bs[8][4];
    const unsigned wid = tid >> 6;
    if ((tid & 63u) == 0u) {
#pragma unroll
        for (int p = 0; p < 4; ++p) bs[wid][p] = s[p];
    }
    __syncthreads();
    if (tid < 4) {
        float v = 0.f;
#pragma unroll
        for (int w = 0; w < 8; ++w) v += bs[w][tid];
        part[((size_t)b * NCHUNK + blockIdx.x) * 4 + tid] = v;
    }
}

// ---------------- Pass 1.5: finalize 32 argmax indices ----------------
__global__ __launch_bounds__(128) void finalize_idx(const float* __restrict__ part,
                                                    int* __restrict__ pidx) {
    const int t = threadIdx.x;            // 128 = 32 batches x 4 phases
    const int b = t >> 2, p = t & 3;
    float s = 0.f;
    for (int c = 0; c < NCHUNK; ++c) s += part[b * (NCHUNK * 4) + c * 4 + p];
    const int g = t & ~3;
    const float v0 = __shfl(s, g + 0), v1 = __shfl(s, g + 1);
    const float v2 = __shfl(s, g + 2), v3 = __shfl(s, g + 3);
    if (p == 0) {
        int idx = 0; float best = v0;
        if (v1 > best) { best = v1; idx = 1; }
        if (v2 > best) { best = v2; idx = 2; }
        if (v3 > best) { best = v3; idx = 3; }
        pidx[b] = idx;
    }
}

// ---------------- Pass 2: h-fused blur + phase select ----------------
// Block = 28 output rows of one plane (2 blocks/plane). 256 threads, 13.2 KB LDS.
// Stage h (horizontal [1,3,3,1]) for union row range r=0..58 (input j=2*oh0+r-1,
// reflect), cols split into middle segs (s=1..5) and edge pairs (s=0,6).
__global__ __launch_bounds__(256) void blur_select(const float* __restrict__ inp,
                                                   const int* __restrict__ pidx,
                                                   float* __restrict__ out) {
    __shared__ float h[59 * 56];
    const int blk = blockIdx.x;
    const int bc  = blk >> 1;
    const int oh0 = (blk & 1) * 28;
    const int t   = threadIdx.x;

    const int phase = pidx[bc >> 7];
    const int dr = phase & 1, dc = phase >> 1;
    const float* P = inp + (size_t)bc * HW_;
    const int jbase = 2 * oh0 - 1;

    // ---- Loop A: middle segs. task q -> row rr=q/5, seg s=1+q%5, h cols 8s..8s+7
    for (int q = t; q < 59 * 5; q += 256) {
        const int rr = q / 5;
        const int s  = 1 + (q - 5 * rr);
        int j = jbase + rr;
        int aj = j < 0 ? -j : j;
        j = aj < 222 - aj ? aj : 222 - aj;
        const float4* rp = (const float4*)(P + j * W_) + (4 * s - 1);
        float4 va[6];
#pragma unroll
        for (int i = 0; i < 6; ++i) va[i] = rp[i];
        float xa[24];
#pragma unroll
        for (int i = 0; i < 6; ++i) {
            xa[4 * i + 0] = va[i].x; xa[4 * i + 1] = va[i].y;
            xa[4 * i + 2] = va[i].z; xa[4 * i + 3] = va[i].w;
        }
        float hh[8];
        if (dc == 0) {
#pragma unroll
            for (int u = 0; u < 8; ++u)
                hh[u] = (xa[2*u+3] + xa[2*u+6]) + 3.f * (xa[2*u+4] + xa[2*u+5]);
        } else {
#pragma unroll
            for (int u = 0; u < 8; ++u)
                hh[u] = (xa[2*u+4] + xa[2*u+7]) + 3.f * (xa[2*u+5] + xa[2*u+6]);
        }
        float* dst = &h[rr * 56 + 8 * s];
        *(float4*)dst       = make_float4(hh[0], hh[1], hh[2], hh[3]);
        *(float4*)(dst + 4) = make_float4(hh[4], hh[5], hh[6], hh[7]);
    }

    // ---- Loop B: edge segs s=0 (h cols 0..7) and s=6 (h cols 48..55), one task/row
    for (int rr = t; rr < 59; rr += 256) {
        int j = jbase + rr;
        int aj = j < 0 ? -j : j;
        j = aj < 222 - aj ? aj : 222 - aj;
        const float4* rp = (const float4*)(P + j * W_);
        float4 a4[5], b4[5];
#pragma unroll
        for (int i = 0; i < 5; ++i) { a4[i] = rp[i]; b4[i] = rp[23 + i]; }
        float xa[20], xb[22];
#pragma unroll
        for (int i = 0; i < 5; ++i) {
            xa[4*i+0] = a4[i].x; xa[4*i+1] = a4[i].y; xa[4*i+2] = a4[i].z; xa[4*i+3] = a4[i].w;
            xb[4*i+0] = b4[i].x; xb[4*i+1] = b4[i].y; xb[4*i+2] = b4[i].z; xb[4*i+3] = b4[i].w;
        }
        xb[20] = xb[18];   // col 112 -> 110
        xb[21] = xb[17];   // col 113 -> 109
        float hl[8], hr[8];
        if (dc == 0) {
            hl[0] = (xa[1] + xa[2]) + 3.f * (xa[0] + xa[1]);   // col -1 -> 1
#pragma unroll
            for (int u = 1; u < 8; ++u)
                hl[u] = (xa[2*u-1] + xa[2*u+2]) + 3.f * (xa[2*u] + xa[2*u+1]);
#pragma unroll
            for (int u = 0; u < 8; ++u)
                hr[u] = (xb[2*u+3] + xb[2*u+6]) + 3.f * (xb[2*u+4] + xb[2*u+5]);
        } else {
#pragma unroll
            for (int u = 0; u < 8; ++u)
                hl[u] = (xa[2*u] + xa[2*u+3]) + 3.f * (xa[2*u+1] + xa[2*u+2]);
#pragma unroll
            for (int u = 0; u < 8; ++u)
                hr[u] = (xb[2*u+4] + xb[2*u+7]) + 3.f * (xb[2*u+5] + xb[2*u+6]);
        }
        float* dl = &h[rr * 56];
        *(float4*)dl        = make_float4(hl[0], hl[1], hl[2], hl[3]);
        *(float4*)(dl + 4)  = make_float4(hl[4], hl[5], hl[6], hl[7]);
        *(float4*)(dl + 48) = make_float4(hr[0], hr[1], hr[2], hr[3]);
        *(float4*)(dl + 52) = make_float4(hr[4], hr[5], hr[6], hr[7]);
    }

    __syncthreads();

    // ---- v-pass: 392 float4 tasks (28 rows x 14), 4 ds_read_b128 each
    float* o = out + (size_t)bc * OHW_ + oh0 * OW_;
    for (int v = t; v < 392; v += 256) {
        const int ohl = v / 14;
        const int q   = v - 14 * ohl;
        const float* hb = &h[(2 * ohl + dr) * 56 + 4 * q];
        const float4 h0 = *(const float4*)hb;
        const float4 h1 = *(const float4*)(hb + 56);
        const float4 h2 = *(const float4*)(hb + 112);
        const float4 h3 = *(const float4*)(hb + 168);
        float4 r;
        r.x = ((h0.x + h3.x) + 3.f * (h1.x + h2.x)) * 0.015625f;
        r.y = ((h0.y + h3.y) + 3.f * (h1.y + h2.y)) * 0.015625f;
        r.z = ((h0.z + h3.z) + 3.f * (h1.z + h2.z)) * 0.015625f;
        r.w = ((h0.w + h3.w) + 3.f * (h1.w + h2.w)) * 0.015625f;
        *(float4*)&o[ohl * 56 + 4 * q] = r;
    }
}

extern "C" void kernel_launch(void* const* d_in, const int* in_sizes, int n_in,
                              void* d_out, int out_size, void* d_ws, size_t ws_size,
                              hipStream_t stream) {
    const float* inp = (const float*)d_in[0];
    float* part = (float*)d_ws;                       // 32*49*4 floats = 25088 B
    int* pidx = (int*)((char*)d_ws + 32 * NCHUNK * 4 * sizeof(float));
    phase_norms<<<dim3(NCHUNK, 32), 512, 0, stream>>>(inp, part);
    finalize_idx<<<1, 128, 0, stream>>>(part, pidx);
    blur_select<<<8192, 256, 0, stream>>>(inp, pidx, (float*)d_out);
}